// Round 6
// baseline (1684.076 us; speedup 1.0000x reference)
//
#include <hip/hip_runtime.h>

// Sizes (static, from reference)
#define NSUB 65536
#define NV0 10242
#define NV1 40962
#define NV2 163842
#define EPSV 1e-5f
#define NSLOT 64
#define GRID 1024

struct Params {
    const float *sub, *Wsub, *bsub, *Wfc, *bfc;
    const float *u0g, *u0b, *u0W, *u0bias;
    const float *u1g, *u1b, *u1W, *u1bias;
    const float *g0, *b0, *W0, *bias0;
    const float *g1, *b1, *W1, *bias1;
    const float *g2, *b2, *W2, *bias2;
    const int *neigh, *top0, *down0, *top1, *down1;
    float *y1p, *x0, *xA, *xB, *h0, *h1;
    float *st0, *st1, *st2, *st3, *st4;
    unsigned *bar;
    float *out;
};

// smem layout (floats): sW [0,448) | sB [448,472) | sc [472,480) | sh [480,488)
// red [488,492) | stl [512,576).  Phase 1 reuses [0,256) for y1.
#define SM_SB 448
#define SM_SC 472
#define SM_SH 480
#define SM_RED 488
#define SM_STL 512

__device__ inline float wave_red(float v) {
#pragma unroll
    for (int off = 32; off > 0; off >>= 1) v += __shfl_down(v, off, 64);
    return v;
}

// Grid-wide barrier: all GRID blocks co-resident (launch_bounds enforces 4/CU).
__device__ inline void gbar(unsigned* bar, unsigned target) {
    __syncthreads();
    __threadfence();
    if (threadIdx.x == 0) {
        __hip_atomic_fetch_add(bar, 1u, __ATOMIC_RELEASE, __HIP_MEMORY_SCOPE_AGENT);
        while (__hip_atomic_load(bar, __ATOMIC_ACQUIRE, __HIP_MEMORY_SCOPE_AGENT) < target)
            __builtin_amdgcn_s_sleep(2);
    }
    __syncthreads();
    __threadfence();
}

// Reduce 64x16 banked stats -> BN scale/shift in LDS. Ends with syncthreads.
template <int CIN>
__device__ inline void bn_prep(const float* __restrict__ bank, float n,
                               const float* __restrict__ g, const float* __restrict__ b,
                               float* sc, float* sh) {
    int t = threadIdx.x;
    if (t < 64) {
        const float* sp = bank + t * 16;
        float r[16];
#pragma unroll
        for (int i = 0; i < 16; ++i) r[i] = sp[i];
#pragma unroll
        for (int i = 0; i < 16; ++i) r[i] = wave_red(r[i]);
        if (t == 0) {
#pragma unroll
            for (int c = 0; c < CIN; ++c) {
                float m = r[c] / n;
                float var = r[8 + c] / n - m * m;
                float scale = rsqrtf(var + EPSV) * g[c];
                sc[c] = scale;
                sh[c] = b[c] - m * scale;
            }
        }
    }
    __syncthreads();
}

// Per-block stat emit: 4 lane0s wrote stl[wv*16+i]; combine and 16 atomics.
__device__ inline void emit16(float* bankOut, float* smem) {
    int t = threadIdx.x;
    __syncthreads();
    if (t < 16) {
        float* stl = smem + SM_STL;
        float v = stl[t] + stl[16 + t] + stl[32 + t] + stl[48 + t];
        atomicAdd(bankOut + (blockIdx.x & (NSLOT - 1)) * 16 + t, v);
    }
}

// ---------------------------------------------------------------------------
__device__ inline void upconv_phase(const float* xin, int nIn, int nOut,
                                    const float* bankIn, float* bankOut,
                                    const float* g, const float* bvec,
                                    const float* Wm, const float* bias,
                                    const int* top, const int* down,
                                    float* xout, float* smem) {
    float* sW = smem;
    float* sB = smem + SM_SB;
    float* sc = smem + SM_SC;
    float* sh = smem + SM_SH;
    int t = threadIdx.x;
    if (t < 63) sW[t] = Wm[t];
    if (t >= 64 && t < 85) sB[t - 64] = bias[t - 64];
    bn_prep<3>(bankIn, (float)nIn, g, bvec, sc, sh);

    int v = blockIdx.x * 256 + t;
    bool ok = v < nOut;
    float o0 = 0.f, o1 = 0.f, o2 = 0.f;
    if (ok) {
        auto uval = [&](int idx, float* o3) {
            int src = idx / 7;
            int j = idx - src * 7;
            float a0 = xin[src * 3 + 0] * sc[0] + sh[0]; a0 = a0 > 0.f ? a0 : 0.2f * a0;
            float a1 = xin[src * 3 + 1] * sc[1] + sh[1]; a1 = a1 > 0.f ? a1 : 0.2f * a1;
            float a2 = xin[src * 3 + 2] * sc[2] + sh[2]; a2 = a2 > 0.f ? a2 : 0.2f * a2;
#pragma unroll
            for (int c = 0; c < 3; ++c) {
                int rr = j * 3 + c;
                o3[c] = sB[rr] + a0 * sW[rr * 3 + 0] + a1 * sW[rr * 3 + 1] + a2 * sW[rr * 3 + 2];
            }
        };
        if (v < nIn) {
            float o3[3];
            uval(top[v], o3);
            o0 = o3[0]; o1 = o3[1]; o2 = o3[2];
        } else {
            int i = v - nIn;
            float a[3], bb[3];
            uval(down[2 * i], a);
            uval(down[2 * i + 1], bb);
            o0 = 0.5f * (a[0] + a[1]);
            o1 = 0.5f * (a[2] + bb[0]);
            o2 = 0.5f * (bb[1] + bb[2]);
        }
        xout[(size_t)v * 3 + 0] = o0;
        xout[(size_t)v * 3 + 1] = o1;
        xout[(size_t)v * 3 + 2] = o2;
    }
    if ((unsigned)(blockIdx.x * 256) < (unsigned)nOut) {   // block-uniform
        float r[16];
#pragma unroll
        for (int i = 0; i < 16; ++i) r[i] = 0.f;
        r[0] = o0; r[1] = o1; r[2] = o2;
        r[8] = o0 * o0; r[9] = o1 * o1; r[10] = o2 * o2;
#pragma unroll
        for (int i = 0; i < 16; ++i) r[i] = wave_red(r[i]);
        if ((t & 63) == 0) {
            float* stl = smem + SM_STL + (t >> 6) * 16;
#pragma unroll
            for (int i = 0; i < 16; ++i) stl[i] = r[i];
        }
        emit16(bankOut, smem);
    }
}

// ---------------------------------------------------------------------------
template <int CIN, int COUT, bool STATS>
__device__ inline void onering_phase(const float* xin, const int* neigh,
                                     const float* Wm, const float* bias,
                                     const float* g, const float* bvec,
                                     const float* bankIn, float* bankOut,
                                     float* out, float* smem) {
    float* sW = smem;
    float* sB = smem + SM_SB;
    float* sc = smem + SM_SC;
    float* sh = smem + SM_SH;
    int t = threadIdx.x;
    for (int i = t; i < COUT * 7 * CIN; i += 256) sW[i] = Wm[i];
    if (t >= 64 && t < 64 + COUT) sB[t - 64] = bias[t - 64];
    bn_prep<CIN>(bankIn, (float)NV2, g, bvec, sc, sh);

    int v = blockIdx.x * 256 + t;
    bool ok = v < NV2;
    float acc[COUT];
#pragma unroll
    for (int c = 0; c < COUT; ++c) acc[c] = 0.f;
    if (ok) {
#pragma unroll
        for (int c = 0; c < COUT; ++c) acc[c] = sB[c];
        const int* np = neigh + (size_t)v * 7;
#pragma unroll
        for (int j = 0; j < 7; ++j) {
            int nb = np[j];
            float tv[CIN];
            if (CIN == 8) {
                float4 A = *(const float4*)(xin + (size_t)nb * 8);
                float4 Bv = *(const float4*)(xin + (size_t)nb * 8 + 4);
                float raw[8] = {A.x, A.y, A.z, A.w, Bv.x, Bv.y, Bv.z, Bv.w};
#pragma unroll
                for (int k = 0; k < 8; ++k) {
                    float x = raw[k] * sc[k] + sh[k];
                    tv[k] = x > 0.f ? x : 0.2f * x;
                }
            } else {
#pragma unroll
                for (int k = 0; k < CIN; ++k) {
                    float x = xin[(size_t)nb * CIN + k] * sc[k] + sh[k];
                    tv[k] = x > 0.f ? x : 0.2f * x;
                }
            }
#pragma unroll
            for (int c = 0; c < COUT; ++c) {
                float a = acc[c];
#pragma unroll
                for (int k = 0; k < CIN; ++k) a += tv[k] * sW[c * 7 * CIN + j * CIN + k];
                acc[c] = a;
            }
        }
        if (COUT == 8) {
            float4 A = {acc[0], acc[1], acc[2], acc[3]};
            float4 Bv = {acc[4], acc[5], acc[6], acc[7]};
            *(float4*)(out + (size_t)v * 8) = A;
            *(float4*)(out + (size_t)v * 8 + 4) = Bv;
        } else {
#pragma unroll
            for (int c = 0; c < COUT; ++c) out[(size_t)v * COUT + c] = acc[c];
        }
    }
    if (STATS) {
        if (blockIdx.x * 256 < NV2) {   // block-uniform
            float r[16];
#pragma unroll
            for (int i = 0; i < 16; ++i) r[i] = 0.f;
#pragma unroll
            for (int c = 0; c < COUT; ++c) { r[c] = acc[c]; r[8 + c] = acc[c] * acc[c]; }
#pragma unroll
            for (int i = 0; i < 16; ++i) r[i] = wave_red(r[i]);
            if ((t & 63) == 0) {
                float* stl = smem + SM_STL + (t >> 6) * 16;
#pragma unroll
                for (int i = 0; i < 16; ++i) stl[i] = r[i];
            }
            emit16(bankOut, smem);
        }
    }
}

// ---------------------------------------------------------------------------
__global__ void k_init(float* banks, unsigned* bar) {
    int i = blockIdx.x * 256 + threadIdx.x;
    if (i == 0) *bar = 0u;
    if (i < 5 * NSLOT * 16) banks[i] = 0.f;
}

// ---------------------------------------------------------------------------
__global__ __launch_bounds__(256, 4) void k_mega(Params p) {
    __shared__ float smem[640];
    int t = threadIdx.x;
    int bid = blockIdx.x;

    // ---- phase 0: gemv1 split-K partials. block = (output o, quarter q)
    {
        int o = bid >> 2, q = bid & 3;
        const float* row = p.Wsub + (size_t)o * NSUB + q * 16384;
        const float* sb = p.sub + q * 16384;
        float a0 = 0.f, a1 = 0.f, a2 = 0.f, a3 = 0.f;
#pragma unroll
        for (int j = 0; j < 16; j += 4) {
            int i0 = (t + 256 * j) * 4, i1 = (t + 256 * (j + 1)) * 4;
            int i2 = (t + 256 * (j + 2)) * 4, i3 = (t + 256 * (j + 3)) * 4;
            float4 xa = *(const float4*)(sb + i0), wa = *(const float4*)(row + i0);
            float4 xb = *(const float4*)(sb + i1), wb = *(const float4*)(row + i1);
            float4 xc = *(const float4*)(sb + i2), wc = *(const float4*)(row + i2);
            float4 xd = *(const float4*)(sb + i3), wd = *(const float4*)(row + i3);
            a0 += xa.x * wa.x + xa.y * wa.y + xa.z * wa.z + xa.w * wa.w;
            a1 += xb.x * wb.x + xb.y * wb.y + xb.z * wb.z + xb.w * wb.w;
            a2 += xc.x * wc.x + xc.y * wc.y + xc.z * wc.z + xc.w * wc.w;
            a3 += xd.x * wd.x + xd.y * wd.y + xd.z * wd.z + xd.w * wd.w;
        }
        float acc = wave_red((a0 + a1) + (a2 + a3));
        if ((t & 63) == 0) smem[SM_RED + (t >> 6)] = acc;
        __syncthreads();
        if (t == 0)
            p.y1p[bid] = smem[SM_RED] + smem[SM_RED + 1] + smem[SM_RED + 2] + smem[SM_RED + 3];
    }
    gbar(p.bar, 1 * GRID);

    // ---- phase 1: y1 reduce (to LDS) + gemv2 + x0 stats
    {
        float yv = p.bsub[t] + p.y1p[t * 4] + p.y1p[t * 4 + 1] +
                   p.y1p[t * 4 + 2] + p.y1p[t * 4 + 3];
        smem[t] = yv;
        __syncthreads();
        int wv = t >> 6, ln = t & 63;
        float4 y4 = *(const float4*)(smem + ln * 4);
        float s0 = 0, s1 = 0, s2 = 0, q0 = 0, q1 = 0, q2 = 0;
#pragma unroll
        for (int it = 0; it < 8; ++it) {
            int o = it * 4096 + bid * 4 + wv;
            if (o < 3 * NV0) {
                const float* row = p.Wfc + (size_t)o * 256;
                float4 w4 = *(const float4*)(row + ln * 4);
                float acc = wave_red(w4.x * y4.x + w4.y * y4.y + w4.z * y4.z + w4.w * y4.w);
                if (ln == 0) {
                    float val = acc + p.bfc[o];
                    p.x0[o] = val;
                    int ch = o % 3;
                    if (ch == 0) { s0 += val; q0 += val * val; }
                    else if (ch == 1) { s1 += val; q1 += val * val; }
                    else { s2 += val; q2 += val * val; }
                }
            }
        }
        if (ln == 0) {
            float* stl = smem + SM_STL + wv * 16;
            stl[0] = s0; stl[1] = s1; stl[2] = s2;
            stl[3] = 0; stl[4] = 0; stl[5] = 0; stl[6] = 0; stl[7] = 0;
            stl[8] = q0; stl[9] = q1; stl[10] = q2;
            stl[11] = 0; stl[12] = 0; stl[13] = 0; stl[14] = 0; stl[15] = 0;
        }
        emit16(p.st0, smem);
    }
    gbar(p.bar, 2 * GRID);

    upconv_phase(p.x0, NV0, NV1, p.st0, p.st1, p.u0g, p.u0b, p.u0W, p.u0bias,
                 p.top0, p.down0, p.xA, smem);
    gbar(p.bar, 3 * GRID);

    upconv_phase(p.xA, NV1, NV2, p.st1, p.st2, p.u1g, p.u1b, p.u1W, p.u1bias,
                 p.top1, p.down1, p.xB, smem);
    gbar(p.bar, 4 * GRID);

    onering_phase<3, 8, true>(p.xB, p.neigh, p.W0, p.bias0, p.g0, p.b0,
                              p.st2, p.st3, p.h0, smem);
    gbar(p.bar, 5 * GRID);

    onering_phase<8, 8, true>(p.h0, p.neigh, p.W1, p.bias1, p.g1, p.b1,
                              p.st3, p.st4, p.h1, smem);
    gbar(p.bar, 6 * GRID);

    onering_phase<8, 2, false>(p.h1, p.neigh, p.W2, p.bias2, p.g2, p.b2,
                               p.st4, nullptr, p.out, smem);
}

// ---------------------------------------------------------------------------
extern "C" void kernel_launch(void* const* d_in, const int* in_sizes, int n_in,
                              void* d_out, int out_size, void* d_ws, size_t ws_size,
                              hipStream_t stream) {
    float* ws = (float*)d_ws;
    Params p;
    p.sub    = (const float*)d_in[0];
    p.Wsub   = (const float*)d_in[1];
    p.bsub   = (const float*)d_in[2];
    p.Wfc    = (const float*)d_in[3];
    p.bfc    = (const float*)d_in[4];
    p.u0g    = (const float*)d_in[5];
    p.u0b    = (const float*)d_in[6];
    p.u0W    = (const float*)d_in[7];
    p.u0bias = (const float*)d_in[8];
    p.u1g    = (const float*)d_in[9];
    p.u1b    = (const float*)d_in[10];
    p.u1W    = (const float*)d_in[11];
    p.u1bias = (const float*)d_in[12];
    p.g0     = (const float*)d_in[13];
    p.b0     = (const float*)d_in[14];
    p.W0     = (const float*)d_in[15];
    p.bias0  = (const float*)d_in[16];
    p.g1     = (const float*)d_in[17];
    p.b1     = (const float*)d_in[18];
    p.W1     = (const float*)d_in[19];
    p.bias1  = (const float*)d_in[20];
    p.g2     = (const float*)d_in[21];
    p.b2     = (const float*)d_in[22];
    p.W2     = (const float*)d_in[23];
    p.bias2  = (const float*)d_in[24];
    p.neigh  = (const int*)d_in[25];
    p.top0   = (const int*)d_in[26];
    p.down0  = (const int*)d_in[27];
    p.top1   = (const int*)d_in[28];
    p.down1  = (const int*)d_in[29];

    p.y1p = ws + 0;
    p.x0  = ws + 4096;
    p.xA  = ws + 40960;
    p.xB  = ws + 167936;
    p.h0  = ws + 663552;
    p.h1  = ws + 1980416;
    float* banks = ws + 3293184;
    p.st0 = banks + 0 * NSLOT * 16;
    p.st1 = banks + 1 * NSLOT * 16;
    p.st2 = banks + 2 * NSLOT * 16;
    p.st3 = banks + 3 * NSLOT * 16;
    p.st4 = banks + 4 * NSLOT * 16;
    p.bar = (unsigned*)(ws + 3298304);
    p.out = (float*)d_out;

    k_init<<<20, 256, 0, stream>>>(banks, p.bar);
    k_mega<<<GRID, 256, 0, stream>>>(p);
}

// Round 7
// 269.520 us; speedup vs baseline: 6.2484x; 6.2484x over previous
//
#include <hip/hip_runtime.h>

// Sizes (static, from reference)
#define NSUB 65536
#define NV0 10242
#define NV1 40962
#define NV2 163842
#define EPSV 1e-5f
#define SPLITK 16
#define NSLOT 16

__device__ inline float wave_red(float v) {
#pragma unroll
    for (int off = 32; off > 0; off >>= 1) v += __shfl_down(v, off, 64);
    return v;
}

// All threads participate. vals[16] per-thread (zeros where inactive).
// Block-reduces and atomicAdds into bank slot (blockIdx & 15).
__device__ inline void emit_stats(const float* vals, float* __restrict__ bank,
                                  float* stl /*shared [64]*/) {
    int t = threadIdx.x;
    float r[16];
#pragma unroll
    for (int i = 0; i < 16; ++i) r[i] = wave_red(vals[i]);
    if ((t & 63) == 0) {
#pragma unroll
        for (int i = 0; i < 16; ++i) stl[(t >> 6) * 16 + i] = r[i];
    }
    __syncthreads();
    if (t < 16) {
        float v = stl[t] + stl[16 + t] + stl[32 + t] + stl[48 + t];
        atomicAdd(bank + (blockIdx.x & (NSLOT - 1)) * 16 + t, v);
    }
}

// Last block of the grid reduces the bank and writes scale/shift (scsh[0..7]=sc,
// scsh[8..15]=sh). Single ticket atomic per block - no spinning.
__device__ inline void stats_finalize(float* __restrict__ bank, unsigned* __restrict__ cnt,
                                      unsigned nblocks, const float* __restrict__ g,
                                      const float* __restrict__ bvec, float n, int CIN,
                                      float* __restrict__ scsh) {
    __shared__ bool amLast;
    __shared__ float tot[16];
    __syncthreads();                // drain this block's bank atomics
    __threadfence();
    if (threadIdx.x == 0)
        amLast = (atomicAdd(cnt, 1u) == nblocks - 1);
    __syncthreads();
    if (!amLast) return;
    __threadfence();
    int t = threadIdx.x;
    if (t < 16) {
        float s = 0.f;
#pragma unroll
        for (int sl = 0; sl < NSLOT; ++sl)
            s += __hip_atomic_load(bank + sl * 16 + t, __ATOMIC_RELAXED,
                                   __HIP_MEMORY_SCOPE_AGENT);
        tot[t] = s;
    }
    __syncthreads();
    if (t < CIN) {
        float m = tot[t] / n;
        float var = tot[8 + t] / n - m * m;
        float scale = rsqrtf(var + EPSV) * g[t];
        scsh[t] = scale;
        scsh[8 + t] = bvec[t] - m * scale;
    }
}

// ---------------------------------------------------------------------------
// gemv1 split-K partials: y1p[s*256+o] = sub[slice s] . W_sub[o, slice s]
__global__ __launch_bounds__(256) void k_gemv1(const float* __restrict__ sub,
                                               const float* __restrict__ Ws,
                                               float* __restrict__ y1p) {
    int task = blockIdx.x, o = task >> 4, s = task & (SPLITK - 1);
    const float* row = Ws + (size_t)o * NSUB + s * (NSUB / SPLITK);
    const float* sb = sub + s * (NSUB / SPLITK);
    int t = threadIdx.x;
    int i0 = t * 4, i1 = (256 + t) * 4, i2 = (512 + t) * 4, i3 = (768 + t) * 4;
    float4 xa = *(const float4*)(sb + i0), wa = *(const float4*)(row + i0);
    float4 xb = *(const float4*)(sb + i1), wb = *(const float4*)(row + i1);
    float4 xc = *(const float4*)(sb + i2), wc = *(const float4*)(row + i2);
    float4 xd = *(const float4*)(sb + i3), wd = *(const float4*)(row + i3);
    float a0 = xa.x * wa.x + xa.y * wa.y + xa.z * wa.z + xa.w * wa.w;
    float a1 = xb.x * wb.x + xb.y * wb.y + xb.z * wb.z + xb.w * wb.w;
    float a2 = xc.x * wc.x + xc.y * wc.y + xc.z * wc.z + xc.w * wc.w;
    float a3 = xd.x * wd.x + xd.y * wd.y + xd.z * wd.z + xd.w * wd.w;
    float acc = wave_red((a0 + a1) + (a2 + a3));
    __shared__ float red[4];
    if ((t & 63) == 0) red[t >> 6] = acc;
    __syncthreads();
    if (t == 0) y1p[s * 256 + o] = red[0] + red[1] + red[2] + red[3];
}

// ---------------------------------------------------------------------------
// bridge: y1[o] = b_sub[o] + sum_s y1p[s][o]; zero stat banks + tickets
__global__ __launch_bounds__(256) void k_bridge(const float* __restrict__ bs,
                                                const float* __restrict__ y1p,
                                                float* __restrict__ y1,
                                                float* __restrict__ banks,
                                                unsigned* __restrict__ cnts) {
    int t = threadIdx.x;
    float acc = bs[t];
#pragma unroll
    for (int s = 0; s < SPLITK; ++s) acc += y1p[s * 256 + t];
    y1[t] = acc;
    for (int i = t; i < 5 * NSLOT * 16; i += 256) banks[i] = 0.f;
    if (t < 5) cnts[t] = 0u;
}

// ---------------------------------------------------------------------------
// x0[o] = y1 . W_fc[o,:] + b_fc[o]; wave per output
__global__ __launch_bounds__(256) void k_gemv2(const float* __restrict__ y1,
                                               const float* __restrict__ Wf,
                                               const float* __restrict__ bfc,
                                               float* __restrict__ x0) {
    int o = blockIdx.x * 4 + (threadIdx.x >> 6);
    int ln = threadIdx.x & 63;
    if (o >= 3 * NV0) return;
    const float* row = Wf + (size_t)o * 256;
    float4 w4 = *(const float4*)(row + ln * 4);
    float4 yv = *(const float4*)(y1 + ln * 4);
    float acc = wave_red(w4.x * yv.x + w4.y * yv.y + w4.z * yv.z + w4.w * yv.w);
    if (ln == 0) x0[o] = acc + bfc[o];
}

// ---------------------------------------------------------------------------
// stats of x0 [NV0,3] + finalize -> scsh0
__global__ __launch_bounds__(256) void k_stats3(const float* __restrict__ x,
                                                float* __restrict__ bank,
                                                unsigned* __restrict__ cnt,
                                                const float* __restrict__ g,
                                                const float* __restrict__ bvec,
                                                float* __restrict__ scsh) {
    __shared__ float stl[64];
    int t = threadIdx.x;
    float vals[16];
#pragma unroll
    for (int i = 0; i < 16; ++i) vals[i] = 0.f;
    for (int v = blockIdx.x * 256 + t; v < NV0; v += 64 * 256) {
        float a = x[v * 3 + 0], b = x[v * 3 + 1], c = x[v * 3 + 2];
        vals[0] += a; vals[1] += b; vals[2] += c;
        vals[8] += a * a; vals[9] += b * b; vals[10] += c * c;
    }
    emit_stats(vals, bank, stl);
    stats_finalize(bank, cnt, 64, g, bvec, (float)NV0, 3, scsh);
}

// ---------------------------------------------------------------------------
// upconv + banked output stats + last-block finalize (for the NEXT BN)
__global__ __launch_bounds__(256) void k_upconv(const float* __restrict__ xin, int nIn, int nOut,
                                                const float* __restrict__ scshIn,
                                                float* __restrict__ bankOut,
                                                unsigned* __restrict__ cnt, unsigned nblocks,
                                                const float* __restrict__ gN,
                                                const float* __restrict__ bN, float nNorm,
                                                float* __restrict__ scshOut,
                                                const float* __restrict__ W,
                                                const float* __restrict__ bias,
                                                const int* __restrict__ top,
                                                const int* __restrict__ down,
                                                float* __restrict__ xout) {
    __shared__ float sW[63], sB[21], sS[16], stl[64];
    int t = threadIdx.x;
    if (t < 63) sW[t] = W[t];
    if (t >= 64 && t < 85) sB[t - 64] = bias[t - 64];
    if (t >= 96 && t < 112) sS[t - 96] = scshIn[t - 96];
    __syncthreads();

    int v = blockIdx.x * 256 + t;
    bool ok = v < nOut;
    float o0 = 0.f, o1 = 0.f, o2 = 0.f;
    if (ok) {
        auto uval = [&](int idx, float* o3) {
            int src = idx / 7;
            int j = idx - src * 7;
            float a0 = xin[src * 3 + 0] * sS[0] + sS[8];  a0 = a0 > 0.f ? a0 : 0.2f * a0;
            float a1 = xin[src * 3 + 1] * sS[1] + sS[9];  a1 = a1 > 0.f ? a1 : 0.2f * a1;
            float a2 = xin[src * 3 + 2] * sS[2] + sS[10]; a2 = a2 > 0.f ? a2 : 0.2f * a2;
#pragma unroll
            for (int c = 0; c < 3; ++c) {
                int rr = j * 3 + c;
                o3[c] = sB[rr] + a0 * sW[rr * 3 + 0] + a1 * sW[rr * 3 + 1] + a2 * sW[rr * 3 + 2];
            }
        };
        if (v < nIn) {
            float o3[3];
            uval(top[v], o3);
            o0 = o3[0]; o1 = o3[1]; o2 = o3[2];
        } else {
            int i = v - nIn;
            float a[3], bb[3];
            uval(down[2 * i], a);
            uval(down[2 * i + 1], bb);
            o0 = 0.5f * (a[0] + a[1]);
            o1 = 0.5f * (a[2] + bb[0]);
            o2 = 0.5f * (bb[1] + bb[2]);
        }
        xout[(size_t)v * 3 + 0] = o0;
        xout[(size_t)v * 3 + 1] = o1;
        xout[(size_t)v * 3 + 2] = o2;
    }
    float vals[16];
#pragma unroll
    for (int i = 0; i < 16; ++i) vals[i] = 0.f;
    vals[0] = o0; vals[1] = o1; vals[2] = o2;
    vals[8] = o0 * o0; vals[9] = o1 * o1; vals[10] = o2 * o2;
    emit_stats(vals, bankOut, stl);
    stats_finalize(bankOut, cnt, nblocks, gN, bN, nNorm, 3, scshOut);
}

// ---------------------------------------------------------------------------
// one-ring conv + optional banked output stats + finalize
template <int CIN, int COUT, bool EMIT>
__global__ __launch_bounds__(256) void k_onering(const float* __restrict__ xin,
                                                 const float* __restrict__ scshIn,
                                                 float* __restrict__ bankOut,
                                                 unsigned* __restrict__ cnt, unsigned nblocks,
                                                 const float* __restrict__ gN,
                                                 const float* __restrict__ bN,
                                                 float* __restrict__ scshOut,
                                                 const float* __restrict__ W,
                                                 const float* __restrict__ bias,
                                                 const int* __restrict__ neigh,
                                                 float* __restrict__ out) {
    __shared__ float sW[COUT * 7 * CIN], sB[COUT], sS[16], stl[64];
    int t = threadIdx.x;
    for (int i = t; i < COUT * 7 * CIN; i += 256) sW[i] = W[i];
    if (t < COUT) sB[t] = bias[t];
    if (t >= 32 && t < 48) sS[t - 32] = scshIn[t - 32];
    __syncthreads();

    int v = blockIdx.x * 256 + t;
    bool ok = v < NV2;
    float acc[COUT];
#pragma unroll
    for (int c = 0; c < COUT; ++c) acc[c] = 0.f;
    if (ok) {
#pragma unroll
        for (int c = 0; c < COUT; ++c) acc[c] = sB[c];
        const int* np = neigh + (size_t)v * 7;
#pragma unroll
        for (int j = 0; j < 7; ++j) {
            int nb = np[j];
            float tv[CIN];
            if (CIN == 8) {
                float4 A = *(const float4*)(xin + (size_t)nb * 8);
                float4 Bv = *(const float4*)(xin + (size_t)nb * 8 + 4);
                float raw[8] = {A.x, A.y, A.z, A.w, Bv.x, Bv.y, Bv.z, Bv.w};
#pragma unroll
                for (int k = 0; k < 8; ++k) {
                    float x = raw[k] * sS[k] + sS[8 + k];
                    tv[k] = x > 0.f ? x : 0.2f * x;
                }
            } else {
#pragma unroll
                for (int k = 0; k < CIN; ++k) {
                    float x = xin[(size_t)nb * CIN + k] * sS[k] + sS[8 + k];
                    tv[k] = x > 0.f ? x : 0.2f * x;
                }
            }
#pragma unroll
            for (int c = 0; c < COUT; ++c) {
                float a = acc[c];
#pragma unroll
                for (int k = 0; k < CIN; ++k) a += tv[k] * sW[c * 7 * CIN + j * CIN + k];
                acc[c] = a;
            }
        }
        if (COUT == 8) {
            float4 A = {acc[0], acc[1], acc[2], acc[3]};
            float4 Bv = {acc[4], acc[5], acc[6], acc[7]};
            *(float4*)(out + (size_t)v * 8) = A;
            *(float4*)(out + (size_t)v * 8 + 4) = Bv;
        } else {
#pragma unroll
            for (int c = 0; c < COUT; ++c) out[(size_t)v * COUT + c] = acc[c];
        }
    }
    if (EMIT) {
        float vals[16];
#pragma unroll
        for (int i = 0; i < 16; ++i) vals[i] = 0.f;
#pragma unroll
        for (int c = 0; c < COUT; ++c) { vals[c] = acc[c]; vals[8 + c] = acc[c] * acc[c]; }
        emit_stats(vals, bankOut, stl);
        stats_finalize(bankOut, cnt, nblocks, gN, bN, (float)NV2, COUT, scshOut);
    }
}

// ---------------------------------------------------------------------------
extern "C" void kernel_launch(void* const* d_in, const int* in_sizes, int n_in,
                              void* d_out, int out_size, void* d_ws, size_t ws_size,
                              hipStream_t stream) {
    const float* sub_id = (const float*)d_in[0];
    const float* W_sub  = (const float*)d_in[1];
    const float* b_sub  = (const float*)d_in[2];
    const float* W_fc   = (const float*)d_in[3];
    const float* b_fc   = (const float*)d_in[4];
    const float* bn_u0g = (const float*)d_in[5];
    const float* bn_u0b = (const float*)d_in[6];
    const float* up0_W  = (const float*)d_in[7];
    const float* up0_b  = (const float*)d_in[8];
    const float* bn_u1g = (const float*)d_in[9];
    const float* bn_u1b = (const float*)d_in[10];
    const float* up1_W  = (const float*)d_in[11];
    const float* up1_b  = (const float*)d_in[12];
    const float* bn0g   = (const float*)d_in[13];
    const float* bn0b   = (const float*)d_in[14];
    const float* c0_W   = (const float*)d_in[15];
    const float* c0_b   = (const float*)d_in[16];
    const float* bn1g   = (const float*)d_in[17];
    const float* bn1b   = (const float*)d_in[18];
    const float* c1_W   = (const float*)d_in[19];
    const float* c1_b   = (const float*)d_in[20];
    const float* bn2g   = (const float*)d_in[21];
    const float* bn2b   = (const float*)d_in[22];
    const float* c2_W   = (const float*)d_in[23];
    const float* c2_b   = (const float*)d_in[24];
    const int* neigh  = (const int*)d_in[25];
    const int* top0   = (const int*)d_in[26];
    const int* down0  = (const int*)d_in[27];
    const int* top1   = (const int*)d_in[28];
    const int* down1  = (const int*)d_in[29];

    float* ws = (float*)d_ws;
    float* y1p   = ws + 0;          // 4096
    float* y1    = ws + 4096;       // 256
    float* x0    = ws + 4352;       // 30726
    float* xA    = ws + 35080;      // 122886
    float* xB    = ws + 157968;     // 491526
    float* h0    = ws + 649496;     // 1310736 (16B aligned)
    float* h1    = ws + 1960232;    // 1310736 (16B aligned)
    float* banks = ws + 3270968;    // 5 * 256
    float* scsh  = ws + 3272248;    // 5 * 16
    unsigned* cnts = (unsigned*)(ws + 3272328);  // 5

    float* st0 = banks + 0 * NSLOT * 16;
    float* st1 = banks + 1 * NSLOT * 16;
    float* st2 = banks + 2 * NSLOT * 16;
    float* st3 = banks + 3 * NSLOT * 16;
    float* st4 = banks + 4 * NSLOT * 16;
    float* scsh0 = scsh + 0;
    float* scsh1 = scsh + 16;
    float* scsh2 = scsh + 32;
    float* scsh3 = scsh + 48;
    float* scsh4 = scsh + 64;

    const unsigned NB1 = (NV1 + 255) / 256;   // 161
    const unsigned NB2 = (NV2 + 255) / 256;   // 641

    k_gemv1<<<256 * SPLITK, 256, 0, stream>>>(sub_id, W_sub, y1p);
    k_bridge<<<1, 256, 0, stream>>>(b_sub, y1p, y1, banks, cnts);
    k_gemv2<<<(3 * NV0 + 3) / 4, 256, 0, stream>>>(y1, W_fc, b_fc, x0);
    k_stats3<<<64, 256, 0, stream>>>(x0, st0, cnts + 0, bn_u0g, bn_u0b, scsh0);

    k_upconv<<<NB1, 256, 0, stream>>>(x0, NV0, NV1, scsh0, st1, cnts + 1, NB1,
                                      bn_u1g, bn_u1b, (float)NV1, scsh1,
                                      up0_W, up0_b, top0, down0, xA);
    k_upconv<<<NB2, 256, 0, stream>>>(xA, NV1, NV2, scsh1, st2, cnts + 2, NB2,
                                      bn0g, bn0b, (float)NV2, scsh2,
                                      up1_W, up1_b, top1, down1, xB);

    k_onering<3, 8, true><<<NB2, 256, 0, stream>>>(
        xB, scsh2, st3, cnts + 3, NB2, bn1g, bn1b, scsh3,
        c0_W, c0_b, neigh, h0);
    k_onering<8, 8, true><<<NB2, 256, 0, stream>>>(
        h0, scsh3, st4, cnts + 4, NB2, bn2g, bn2b, scsh4,
        c1_W, c1_b, neigh, h1);
    k_onering<8, 2, false><<<NB2, 256, 0, stream>>>(
        h1, scsh4, nullptr, nullptr, 0, nullptr, nullptr, nullptr,
        c2_W, c2_b, neigh, (float*)d_out);
}

// Round 8
// 98.944 us; speedup vs baseline: 17.0204x; 2.7240x over previous
//
#include <hip/hip_runtime.h>

// Sizes (static, from reference)
#define NSUB 65536
#define NV0 10242
#define NV1 40962
#define NV2 163842
#define EPSV 1e-5f
#define SPLITK 16

__device__ inline float wave_red(float v) {
#pragma unroll
    for (int off = 32; off > 0; off >>= 1) v += __shfl_down(v, off, 64);
    return v;
}

// Block-reduce vals[16] (layout: [c]=sum, [8+c]=sumsq for c<NCH) and
// atomicAdd into slot (16 floats). All 256 threads must reach this.
// No fences: plain device-scope atomics; cross-kernel visibility via stream order.
template <int NCH>
__device__ inline void emit_stats(const float* vals, float* __restrict__ slot,
                                  float* stl /*shared [64]*/) {
    int t = threadIdx.x;
    float r[2 * NCH];
#pragma unroll
    for (int c = 0; c < NCH; ++c) {
        r[c] = wave_red(vals[c]);
        r[NCH + c] = wave_red(vals[8 + c]);
    }
    if ((t & 63) == 0) {
#pragma unroll
        for (int i = 0; i < 2 * NCH; ++i) stl[(t >> 6) * 16 + i] = r[i];
    }
    __syncthreads();
    if (t < 2 * NCH) {
        float v = stl[t] + stl[16 + t] + stl[32 + t] + stl[48 + t];
        int idx = (t < NCH) ? t : 8 + (t - NCH);
        atomicAdd(slot + idx, v);
    }
}

// Consumer prologue: derive BN scale/shift from raw sums. sS[c]=scale, sS[8+c]=shift.
template <int NCH>
__device__ inline void bn_from_sums(const float* __restrict__ slot, float n,
                                    const float* __restrict__ g,
                                    const float* __restrict__ b, float* sS) {
    int t = threadIdx.x;
    if (t < NCH) {
        float m = slot[t] / n;
        float var = slot[8 + t] / n - m * m;
        float scale = rsqrtf(var + EPSV) * g[t];
        sS[t] = scale;
        sS[8 + t] = b[t] - m * scale;
    }
}

// ---------------------------------------------------------------------------
// gemv1 split-K partials: y1p[s*256+o] = sub[slice s] . W_sub[o, slice s]
__global__ __launch_bounds__(256) void k_gemv1(const float* __restrict__ sub,
                                               const float* __restrict__ Ws,
                                               float* __restrict__ y1p) {
    int task = blockIdx.x, o = task >> 4, s = task & (SPLITK - 1);
    const float* row = Ws + (size_t)o * NSUB + s * (NSUB / SPLITK);
    const float* sb = sub + s * (NSUB / SPLITK);
    int t = threadIdx.x;
    int i0 = t * 4, i1 = (256 + t) * 4, i2 = (512 + t) * 4, i3 = (768 + t) * 4;
    float4 xa = *(const float4*)(sb + i0), wa = *(const float4*)(row + i0);
    float4 xb = *(const float4*)(sb + i1), wb = *(const float4*)(row + i1);
    float4 xc = *(const float4*)(sb + i2), wc = *(const float4*)(row + i2);
    float4 xd = *(const float4*)(sb + i3), wd = *(const float4*)(row + i3);
    float a0 = xa.x * wa.x + xa.y * wa.y + xa.z * wa.z + xa.w * wa.w;
    float a1 = xb.x * wb.x + xb.y * wb.y + xb.z * wb.z + xb.w * wb.w;
    float a2 = xc.x * wc.x + xc.y * wc.y + xc.z * wc.z + xc.w * wc.w;
    float a3 = xd.x * wd.x + xd.y * wd.y + xd.z * wd.z + xd.w * wd.w;
    float acc = wave_red((a0 + a1) + (a2 + a3));
    __shared__ float red[4];
    if ((t & 63) == 0) red[t >> 6] = acc;
    __syncthreads();
    if (t == 0) y1p[s * 256 + o] = red[0] + red[1] + red[2] + red[3];
}

// ---------------------------------------------------------------------------
// bridge: y1[o] = b_sub[o] + sum_s y1p[s][o]; zero the 5x16 stat slots
__global__ __launch_bounds__(256) void k_bridge(const float* __restrict__ bs,
                                                const float* __restrict__ y1p,
                                                float* __restrict__ y1,
                                                float* __restrict__ slots) {
    int t = threadIdx.x;
    float acc = bs[t];
#pragma unroll
    for (int s = 0; s < SPLITK; ++s) acc += y1p[s * 256 + t];
    y1[t] = acc;
    if (t < 80) slots[t] = 0.f;
}

// ---------------------------------------------------------------------------
// x0[o] = y1 . W_fc[o,:] + b_fc[o]; wave per output
__global__ __launch_bounds__(256) void k_gemv2(const float* __restrict__ y1,
                                               const float* __restrict__ Wf,
                                               const float* __restrict__ bfc,
                                               float* __restrict__ x0) {
    int o = blockIdx.x * 4 + (threadIdx.x >> 6);
    int ln = threadIdx.x & 63;
    if (o >= 3 * NV0) return;
    const float* row = Wf + (size_t)o * 256;
    float4 w4 = *(const float4*)(row + ln * 4);
    float4 yv = *(const float4*)(y1 + ln * 4);
    float acc = wave_red(w4.x * yv.x + w4.y * yv.y + w4.z * yv.z + w4.w * yv.w);
    if (ln == 0) x0[o] = acc + bfc[o];
}

// ---------------------------------------------------------------------------
// stats of x0 [NV0,3] -> slot st0 (atomics, no fences)
__global__ __launch_bounds__(256) void k_stats3(const float* __restrict__ x,
                                                float* __restrict__ slot) {
    __shared__ float stl[64];
    int t = threadIdx.x;
    float vals[16];
#pragma unroll
    for (int i = 0; i < 16; ++i) vals[i] = 0.f;
    for (int v = blockIdx.x * 256 + t; v < NV0; v += 64 * 256) {
        float a = x[v * 3 + 0], b = x[v * 3 + 1], c = x[v * 3 + 2];
        vals[0] += a; vals[1] += b; vals[2] += c;
        vals[8] += a * a; vals[9] += b * b; vals[10] += c * c;
    }
    emit_stats<3>(vals, slot, stl);
}

// ---------------------------------------------------------------------------
// upconv + fused output stats (plain atomics)
__global__ __launch_bounds__(256) void k_upconv(const float* __restrict__ xin, int nIn, int nOut,
                                                const float* __restrict__ slotIn,
                                                float* __restrict__ slotOut,
                                                const float* __restrict__ gIn,
                                                const float* __restrict__ bIn,
                                                const float* __restrict__ W,
                                                const float* __restrict__ bias,
                                                const int* __restrict__ top,
                                                const int* __restrict__ down,
                                                float* __restrict__ xout) {
    __shared__ float sW[63], sB[21], sS[16], stl[64];
    int t = threadIdx.x;
    if (t >= 64 && t < 127) sW[t - 64] = W[t - 64];
    if (t >= 128 && t < 149) sB[t - 128] = bias[t - 128];
    bn_from_sums<3>(slotIn, (float)nIn, gIn, bIn, sS);
    __syncthreads();

    int v = blockIdx.x * 256 + t;
    bool ok = v < nOut;
    float o0 = 0.f, o1 = 0.f, o2 = 0.f;
    if (ok) {
        auto uval = [&](int idx, float* o3) {
            int src = idx / 7;
            int j = idx - src * 7;
            float a0 = xin[src * 3 + 0] * sS[0] + sS[8];  a0 = a0 > 0.f ? a0 : 0.2f * a0;
            float a1 = xin[src * 3 + 1] * sS[1] + sS[9];  a1 = a1 > 0.f ? a1 : 0.2f * a1;
            float a2 = xin[src * 3 + 2] * sS[2] + sS[10]; a2 = a2 > 0.f ? a2 : 0.2f * a2;
#pragma unroll
            for (int c = 0; c < 3; ++c) {
                int rr = j * 3 + c;
                o3[c] = sB[rr] + a0 * sW[rr * 3 + 0] + a1 * sW[rr * 3 + 1] + a2 * sW[rr * 3 + 2];
            }
        };
        if (v < nIn) {
            float o3[3];
            uval(top[v], o3);
            o0 = o3[0]; o1 = o3[1]; o2 = o3[2];
        } else {
            int i = v - nIn;
            float a[3], bb[3];
            uval(down[2 * i], a);
            uval(down[2 * i + 1], bb);
            o0 = 0.5f * (a[0] + a[1]);
            o1 = 0.5f * (a[2] + bb[0]);
            o2 = 0.5f * (bb[1] + bb[2]);
        }
        xout[(size_t)v * 3 + 0] = o0;
        xout[(size_t)v * 3 + 1] = o1;
        xout[(size_t)v * 3 + 2] = o2;
    }
    float vals[16];
#pragma unroll
    for (int i = 0; i < 16; ++i) vals[i] = 0.f;
    vals[0] = o0; vals[1] = o1; vals[2] = o2;
    vals[8] = o0 * o0; vals[9] = o1 * o1; vals[10] = o2 * o2;
    emit_stats<3>(vals, slotOut, stl);
}

// ---------------------------------------------------------------------------
// one-ring conv + optional fused output stats
template <int CIN, int COUT, bool EMIT>
__global__ __launch_bounds__(256) void k_onering(const float* __restrict__ xin,
                                                 const float* __restrict__ slotIn,
                                                 float* __restrict__ slotOut,
                                                 const float* __restrict__ gIn,
                                                 const float* __restrict__ bIn,
                                                 const float* __restrict__ W,
                                                 const float* __restrict__ bias,
                                                 const int* __restrict__ neigh,
                                                 float* __restrict__ out) {
    __shared__ float sW[COUT * 7 * CIN], sB[COUT], sS[16], stl[64];
    int t = threadIdx.x;
    for (int i = t; i < COUT * 7 * CIN; i += 256) sW[i] = W[i];
    if (t >= 32 && t < 32 + COUT) sB[t - 32] = bias[t - 32];
    bn_from_sums<CIN>(slotIn, (float)NV2, gIn, bIn, sS);
    __syncthreads();

    int v = blockIdx.x * 256 + t;
    bool ok = v < NV2;
    float acc[COUT];
#pragma unroll
    for (int c = 0; c < COUT; ++c) acc[c] = 0.f;
    if (ok) {
#pragma unroll
        for (int c = 0; c < COUT; ++c) acc[c] = sB[c];
        const int* np = neigh + (size_t)v * 7;
#pragma unroll
        for (int j = 0; j < 7; ++j) {
            int nb = np[j];
            float tv[CIN];
            if (CIN == 8) {
                float4 A = *(const float4*)(xin + (size_t)nb * 8);
                float4 Bv = *(const float4*)(xin + (size_t)nb * 8 + 4);
                float raw[8] = {A.x, A.y, A.z, A.w, Bv.x, Bv.y, Bv.z, Bv.w};
#pragma unroll
                for (int k = 0; k < 8; ++k) {
                    float x = raw[k] * sS[k] + sS[8 + k];
                    tv[k] = x > 0.f ? x : 0.2f * x;
                }
            } else {
#pragma unroll
                for (int k = 0; k < CIN; ++k) {
                    float x = xin[(size_t)nb * CIN + k] * sS[k] + sS[8 + k];
                    tv[k] = x > 0.f ? x : 0.2f * x;
                }
            }
#pragma unroll
            for (int c = 0; c < COUT; ++c) {
                float a = acc[c];
#pragma unroll
                for (int k = 0; k < CIN; ++k) a += tv[k] * sW[c * 7 * CIN + j * CIN + k];
                acc[c] = a;
            }
        }
        if (COUT == 8) {
            float4 A = {acc[0], acc[1], acc[2], acc[3]};
            float4 Bv = {acc[4], acc[5], acc[6], acc[7]};
            *(float4*)(out + (size_t)v * 8) = A;
            *(float4*)(out + (size_t)v * 8 + 4) = Bv;
        } else {
#pragma unroll
            for (int c = 0; c < COUT; ++c) out[(size_t)v * COUT + c] = acc[c];
        }
    }
    if (EMIT) {
        float vals[16];
#pragma unroll
        for (int i = 0; i < 16; ++i) vals[i] = 0.f;
#pragma unroll
        for (int c = 0; c < COUT; ++c) { vals[c] = acc[c]; vals[8 + c] = acc[c] * acc[c]; }
        emit_stats<COUT>(vals, slotOut, stl);
    }
}

// ---------------------------------------------------------------------------
extern "C" void kernel_launch(void* const* d_in, const int* in_sizes, int n_in,
                              void* d_out, int out_size, void* d_ws, size_t ws_size,
                              hipStream_t stream) {
    const float* sub_id = (const float*)d_in[0];
    const float* W_sub  = (const float*)d_in[1];
    const float* b_sub  = (const float*)d_in[2];
    const float* W_fc   = (const float*)d_in[3];
    const float* b_fc   = (const float*)d_in[4];
    const float* bn_u0g = (const float*)d_in[5];
    const float* bn_u0b = (const float*)d_in[6];
    const float* up0_W  = (const float*)d_in[7];
    const float* up0_b  = (const float*)d_in[8];
    const float* bn_u1g = (const float*)d_in[9];
    const float* bn_u1b = (const float*)d_in[10];
    const float* up1_W  = (const float*)d_in[11];
    const float* up1_b  = (const float*)d_in[12];
    const float* bn0g   = (const float*)d_in[13];
    const float* bn0b   = (const float*)d_in[14];
    const float* c0_W   = (const float*)d_in[15];
    const float* c0_b   = (const float*)d_in[16];
    const float* bn1g   = (const float*)d_in[17];
    const float* bn1b   = (const float*)d_in[18];
    const float* c1_W   = (const float*)d_in[19];
    const float* c1_b   = (const float*)d_in[20];
    const float* bn2g   = (const float*)d_in[21];
    const float* bn2b   = (const float*)d_in[22];
    const float* c2_W   = (const float*)d_in[23];
    const float* c2_b   = (const float*)d_in[24];
    const int* neigh  = (const int*)d_in[25];
    const int* top0   = (const int*)d_in[26];
    const int* down0  = (const int*)d_in[27];
    const int* top1   = (const int*)d_in[28];
    const int* down1  = (const int*)d_in[29];

    float* ws = (float*)d_ws;
    float* y1p   = ws + 0;          // 4096
    float* y1    = ws + 4096;       // 256
    float* x0    = ws + 4352;       // 30726
    float* xA    = ws + 35080;      // 122886
    float* xB    = ws + 157968;     // 491526
    float* h0    = ws + 649496;     // 1310736 (16B aligned)
    float* h1    = ws + 1960232;    // 1310736 (16B aligned)
    float* slots = ws + 3270968;    // 5 * 16

    float* st0 = slots + 0;
    float* st1 = slots + 16;
    float* st2 = slots + 32;
    float* st3 = slots + 48;
    float* st4 = slots + 64;

    const unsigned NB1 = (NV1 + 255) / 256;   // 161
    const unsigned NB2 = (NV2 + 255) / 256;   // 641

    k_gemv1<<<256 * SPLITK, 256, 0, stream>>>(sub_id, W_sub, y1p);
    k_bridge<<<1, 256, 0, stream>>>(b_sub, y1p, y1, slots);
    k_gemv2<<<(3 * NV0 + 3) / 4, 256, 0, stream>>>(y1, W_fc, b_fc, x0);
    k_stats3<<<64, 256, 0, stream>>>(x0, st0);

    k_upconv<<<NB1, 256, 0, stream>>>(x0, NV0, NV1, st0, st1,
                                      bn_u0g, bn_u0b, up0_W, up0_b, top0, down0, xA);
    k_upconv<<<NB2, 256, 0, stream>>>(xA, NV1, NV2, st1, st2,
                                      bn_u1g, bn_u1b, up1_W, up1_b, top1, down1, xB);

    k_onering<3, 8, true><<<NB2, 256, 0, stream>>>(
        xB, st2, st3, bn0g, bn0b, c0_W, c0_b, neigh, h0);
    k_onering<8, 8, true><<<NB2, 256, 0, stream>>>(
        h0, st3, st4, bn1g, bn1b, c1_W, c1_b, neigh, h1);
    k_onering<8, 2, false><<<NB2, 256, 0, stream>>>(
        h1, st4, nullptr, bn2g, bn2b, c2_W, c2_b, neigh, (float*)d_out);
}